// Round 5
// baseline (1348.561 us; speedup 1.0000x reference)
//
#include <hip/hip_runtime.h>
#include <hip/hip_bf16.h>

// AdaptFormer — Round 4:
//  * XCD-aligned M-major GEMM grids (grid.x = M-tiles padded to x8) -> same-M
//    N-tiles share an XCD's L2; fc2 FETCH 172MB -> ~110MB predicted
//  * BK=64 (2 MFMA k-steps/barrier), TM=64 tiles for N=768 GEMMs (2x blocks)
//  * down fused into fc1 (N=3136, per-col act select); LN1 fused into
//    attend_fused; flash-attn grid bh-major for KV L2 reuse

#define H_HEADS 12
#define DMODEL 768
#define DFF 3072
#define ADIM 64
#define NLAT 32
#define BATCH 16
#define NA 512
#define NV 196
#define NTOT 708
#define MCAT (BATCH * NTOT)  // 11328

typedef __hip_bfloat16 bf16;
using bf16x8 = __attribute__((ext_vector_type(8))) short;
using f32x4  = __attribute__((ext_vector_type(4))) float;

static __device__ __forceinline__ float bf2f(bf16 v) { return __bfloat162float(v); }
static __device__ __forceinline__ float bflo(unsigned u) { return __uint_as_float(u << 16); }
static __device__ __forceinline__ float ld1(const float* p) { return *p; }
static __device__ __forceinline__ float ld1(const bf16* p) { return bf2f(*p); }
static __device__ __forceinline__ unsigned short f2bf_bits(float v) {
    unsigned u = __float_as_uint(v);
    return (unsigned short)((u + 0x7fffu + ((u >> 16) & 1u)) >> 16);
}

#define GLD_LDS16(gp, lp) __builtin_amdgcn_global_load_lds( \
    (const __attribute__((address_space(1))) void*)(gp), \
    (__attribute__((address_space(3))) void*)(lp), 16, 0, 0)

static inline int pad8(int v) { return (v + 7) & ~7; }

// ---------------------------------------------------------------------------
__global__ void detect_dtype_kernel(const unsigned short* __restrict__ x, int* __restrict__ flag)
{
    if (threadIdx.x == 0 && blockIdx.x == 0) {
        int big = 0;
        for (int i = 0; i < 2048; i++) {
            unsigned e = (x[i] >> 7) & 0xFF;
            if (e >= 0x90) big++;
        }
        flag[0] = (big > 16) ? 1 : 0;
        flag[1] = 0;
    }
}

// ---------------------------------------------------------------------------
// Pack concat -> Cc bf16 [MCAT,768]; latents -> Lb bf16 [32,768]
// ---------------------------------------------------------------------------
template<typename TIn>
static __device__ __forceinline__ void pack_body(
    const TIn* __restrict__ x, const TIn* __restrict__ y, const TIn* __restrict__ lat,
    bf16* __restrict__ Cc, bf16* __restrict__ Lb)
{
    const int r = blockIdx.x, tid = threadIdx.x;
    const TIn* src;
    bf16* dst;
    if (r < MCAT) {
        const int b = r / NTOT, n = r - b * NTOT;
        src = (n < NA) ? x + ((size_t)(b * NA + n)) * DMODEL
                       : y + ((size_t)(b * NV + (n - NA))) * DMODEL;
        dst = Cc + (size_t)r * DMODEL;
    } else {
        src = lat + (size_t)(r - MCAT) * DMODEL;
        dst = Lb + (size_t)(r - MCAT) * DMODEL;
    }
    dst[tid]       = __float2bfloat16(ld1(src + tid));
    dst[tid + 256] = __float2bfloat16(ld1(src + tid + 256));
    dst[tid + 512] = __float2bfloat16(ld1(src + tid + 512));
}

__global__ __launch_bounds__(256)
void pack_concat_kernel(const int* __restrict__ flag, const void* x, const void* y,
                        const void* lat, bf16* __restrict__ Cc, bf16* __restrict__ Lb)
{
    if (flag[0]) pack_body<float>((const float*)x, (const float*)y, (const float*)lat, Cc, Lb);
    else         pack_body<bf16>((const bf16*)x, (const bf16*)y, (const bf16*)lat, Cc, Lb);
}

// ---------------------------------------------------------------------------
// Fusion softmax: P[b][l][n] over n=708, rows zero-padded to 768
// ---------------------------------------------------------------------------
__global__ __launch_bounds__(64)
void fusion_softmax_kernel(const float* __restrict__ scores, float* __restrict__ P)
{
    const int b = blockIdx.x >> 5, l = blockIdx.x & 31, lane = threadIdx.x;
    const float* sp = scores + (size_t)b * NTOT * NLAT + l;
    float v[12];
    float mx = -1e30f;
    #pragma unroll
    for (int i = 0; i < 12; i++) {
        const int n = lane + i * 64;
        v[i] = (n < NTOT) ? sp[(size_t)n * NLAT] * 0.03608439182435161f : -1e30f;
        mx = fmaxf(mx, v[i]);
    }
    #pragma unroll
    for (int off = 32; off; off >>= 1) mx = fmaxf(mx, __shfl_xor(mx, off));
    float den = 0.f;
    #pragma unroll
    for (int i = 0; i < 12; i++) { v[i] = __expf(v[i] - mx); den += v[i]; }
    #pragma unroll
    for (int off = 32; off; off >>= 1) den += __shfl_xor(den, off);
    const float inv = 1.0f / den;
    float* op = P + ((size_t)b * NLAT + l) * 768;
    #pragma unroll
    for (int i = 0; i < 12; i++) {
        const int n = lane + i * 64;
        op[n] = (n < NTOT) ? v[i] * inv : 0.f;
    }
}

// ---------------------------------------------------------------------------
// Weighted sum: fused[b][l][d] = sum_n P[b][l][n] * Cc[b*708+n][d]
// ---------------------------------------------------------------------------
__global__ __launch_bounds__(256)
void fusion_wsum_kernel(const bf16* __restrict__ Cc, const float* __restrict__ P,
                        bf16* __restrict__ fused)
{
    const int b = blockIdx.y, d0 = blockIdx.x * 128;
    const int tid = threadIdx.x;
    const int lg = tid >> 5, dg = tid & 31;
    const int l0 = lg * 4;

    __shared__ float Ct[64][132];
    __shared__ float Ps[32][68];

    float acc[4][4] = {};

    for (int nc = 0; nc < 12; nc++) {
        const int n0 = nc * 64;
        __syncthreads();
        #pragma unroll
        for (int it = 0; it < 8; it++) {
            const int idx = it * 1024 + tid * 4;
            const int r = idx >> 7, c = idx & 127;
            const int gn = n0 + r;
            float4 v = make_float4(0.f, 0.f, 0.f, 0.f);
            if (gn < NTOT) {
                const ushort4 u = *(const ushort4*)(Cc + ((size_t)(b * NTOT + gn)) * DMODEL + d0 + c);
                v = make_float4(bflo(u.x), bflo(u.y), bflo(u.z), bflo(u.w));
            }
            Ct[r][c] = v.x; Ct[r][c + 1] = v.y; Ct[r][c + 2] = v.z; Ct[r][c + 3] = v.w;
        }
        {
            const int l = tid >> 3, off = (tid & 7) * 8;
            const float* pp = P + ((size_t)b * NLAT + l) * 768 + n0 + off;
            const float4 p0 = *(const float4*)pp;
            const float4 p1 = *(const float4*)(pp + 4);
            Ps[l][off] = p0.x; Ps[l][off + 1] = p0.y; Ps[l][off + 2] = p0.z; Ps[l][off + 3] = p0.w;
            Ps[l][off + 4] = p1.x; Ps[l][off + 5] = p1.y; Ps[l][off + 6] = p1.z; Ps[l][off + 7] = p1.w;
        }
        __syncthreads();

        for (int n = 0; n < 64; n++) {
            const float4 v = *(const float4*)&Ct[n][dg * 4];
            #pragma unroll
            for (int i = 0; i < 4; i++) {
                const float p = Ps[l0 + i][n];
                acc[i][0] += p * v.x; acc[i][1] += p * v.y;
                acc[i][2] += p * v.z; acc[i][3] += p * v.w;
            }
        }
    }

    #pragma unroll
    for (int i = 0; i < 4; i++) {
        bf16* op = fused + ((size_t)b * NLAT + l0 + i) * DMODEL + d0 + dg * 4;
        #pragma unroll
        for (int j = 0; j < 4; j++) op[j] = __float2bfloat16(acc[i][j]);
    }
}

// ---------------------------------------------------------------------------
// Fusion stage 2 (+ optional fused LN1): t_out = t + scale*attn; out=t_out bf16;
// if hout != null also write ln(t_out)*g+b.
// ---------------------------------------------------------------------------
template<typename TIn>
static __device__ __forceinline__ void attend_fused_body(
    const TIn* __restrict__ t, const bf16* __restrict__ fused,
    const TIn* __restrict__ scale_p, const TIn* __restrict__ lng, const TIn* __restrict__ lnb,
    bf16* __restrict__ out, bf16* __restrict__ hout, int Npb)
{
    const int tid = threadIdx.x;
    const int gid = blockIdx.x;
    const int b = gid / Npb;
    const TIn* row = t + (size_t)gid * DMODEL;
    const bf16* fb = fused + (size_t)b * NLAT * DMODEL;

    __shared__ float q[DMODEL];
    __shared__ float p[NLAT];
    __shared__ float rs[4], rq[4];

    for (int d = tid; d < DMODEL; d += 256) q[d] = ld1(row + d);
    __syncthreads();

    const int g = tid >> 3, li = tid & 7;
    float s = 0.f;
    const bf16* fr = fb + (size_t)g * DMODEL;
    for (int d = li; d < DMODEL; d += 8) s += q[d] * bf2f(fr[d]);
    s += __shfl_xor(s, 1); s += __shfl_xor(s, 2); s += __shfl_xor(s, 4);
    if (li == 0) p[g] = s * 0.03608439182435161f;
    __syncthreads();

    float mx = -1e30f;
    #pragma unroll
    for (int l = 0; l < NLAT; l++) mx = fmaxf(mx, p[l]);
    float w[NLAT];
    float den = 0.f;
    #pragma unroll
    for (int l = 0; l < NLAT; l++) { w[l] = __expf(p[l] - mx); den += w[l]; }
    const float sA = ld1(scale_p) / den;

    float a0 = 0.f, a1 = 0.f, a2 = 0.f;
    #pragma unroll
    for (int l = 0; l < NLAT; l++) {
        const bf16* fv = fb + (size_t)l * DMODEL;
        a0 += w[l] * bf2f(fv[tid]);
        a1 += w[l] * bf2f(fv[tid + 256]);
        a2 += w[l] * bf2f(fv[tid + 512]);
    }
    const float t0v = q[tid] + sA * a0;
    const float t1v = q[tid + 256] + sA * a1;
    const float t2v = q[tid + 512] + sA * a2;
    bf16* o = out + (size_t)gid * DMODEL;
    o[tid]       = __float2bfloat16(t0v);
    o[tid + 256] = __float2bfloat16(t1v);
    o[tid + 512] = __float2bfloat16(t2v);

    if (hout) {  // fused LN1
        float ss = t0v + t1v + t2v;
        float sq = t0v * t0v + t1v * t1v + t2v * t2v;
        #pragma unroll
        for (int off = 32; off; off >>= 1) { ss += __shfl_xor(ss, off); sq += __shfl_xor(sq, off); }
        if ((tid & 63) == 0) { rs[tid >> 6] = ss; rq[tid >> 6] = sq; }
        __syncthreads();
        ss = rs[0] + rs[1] + rs[2] + rs[3];
        sq = rq[0] + rq[1] + rq[2] + rq[3];
        const float mean = ss * (1.0f / DMODEL);
        const float var = sq * (1.0f / DMODEL) - mean * mean;
        const float r = rsqrtf(var + 1e-6f);
        bf16* ho = hout + (size_t)gid * DMODEL;
        ho[tid]       = __float2bfloat16((t0v - mean) * r * ld1(lng + tid)       + ld1(lnb + tid));
        ho[tid + 256] = __float2bfloat16((t1v - mean) * r * ld1(lng + tid + 256) + ld1(lnb + tid + 256));
        ho[tid + 512] = __float2bfloat16((t2v - mean) * r * ld1(lng + tid + 512) + ld1(lnb + tid + 512));
    }
}

__global__ __launch_bounds__(256)
void attend_fused_kernel(const int* __restrict__ flag, const void* t, const bf16* __restrict__ fused,
                         const void* scale_p, const void* lng, const void* lnb,
                         bf16* __restrict__ out, bf16* __restrict__ hout, int Npb)
{
    if (flag[0]) attend_fused_body<float>((const float*)t, fused, (const float*)scale_p,
                                          (const float*)lng, (const float*)lnb, out, hout, Npb);
    else         attend_fused_body<bf16>((const bf16*)t, fused, (const bf16*)scale_p,
                                         (const bf16*)lng, (const bf16*)lnb, out, hout, Npb);
}

// ---------------------------------------------------------------------------
// LayerNorm (bf16 ws in/out) — used for LN2 and chunked-mode LN1
// ---------------------------------------------------------------------------
template<typename TW>
static __device__ __forceinline__ void ln_body(
    const bf16* __restrict__ in, const TW* __restrict__ g,
    const TW* __restrict__ bta, bf16* __restrict__ out)
{
    const int tid = threadIdx.x;
    const bf16* p = in + (size_t)blockIdx.x * DMODEL;
    const float v0 = bf2f(p[tid]), v1 = bf2f(p[tid + 256]), v2 = bf2f(p[tid + 512]);
    float s = v0 + v1 + v2;
    float sq = v0 * v0 + v1 * v1 + v2 * v2;
    #pragma unroll
    for (int off = 32; off; off >>= 1) { s += __shfl_xor(s, off); sq += __shfl_xor(sq, off); }
    __shared__ float rs[4], rq[4];
    if ((tid & 63) == 0) { rs[tid >> 6] = s; rq[tid >> 6] = sq; }
    __syncthreads();
    s = rs[0] + rs[1] + rs[2] + rs[3];
    sq = rq[0] + rq[1] + rq[2] + rq[3];
    const float mean = s * (1.0f / DMODEL);
    const float var = sq * (1.0f / DMODEL) - mean * mean;
    const float r = rsqrtf(var + 1e-6f);
    bf16* o = out + (size_t)blockIdx.x * DMODEL;
    o[tid]       = __float2bfloat16((v0 - mean) * r * ld1(g + tid)       + ld1(bta + tid));
    o[tid + 256] = __float2bfloat16((v1 - mean) * r * ld1(g + tid + 256) + ld1(bta + tid + 256));
    o[tid + 512] = __float2bfloat16((v2 - mean) * r * ld1(g + tid + 512) + ld1(bta + tid + 512));
}

__global__ __launch_bounds__(256)
void ln_kernel(const int* __restrict__ flag, const bf16* __restrict__ in,
               const void* g, const void* b, bf16* __restrict__ out)
{
    if (flag[0]) ln_body<float>(in, (const float*)g, (const float*)b, out);
    else         ln_body<bf16>(in, (const bf16*)g, (const bf16*)b, out);
}

// ---------------------------------------------------------------------------
// Flash MFMA attention. grid: (bh = b*12+h major, qt) for KV L2 locality.
// ---------------------------------------------------------------------------
__global__ __launch_bounds__(256)
void flash_attn_kernel(const bf16* __restrict__ qkv, bf16* __restrict__ o, int Npb)
{
    const int tid = threadIdx.x;
    const int wv = tid >> 6, lane = tid & 63;
    const int l15 = lane & 15, q4 = lane >> 4;
    const int h = blockIdx.x % H_HEADS, bb = blockIdx.x / H_HEADS;
    const int qt = blockIdx.y;
    const int nkv = (Npb + 63) >> 6;
    const size_t tokbase = (size_t)bb * Npb;

    __shared__ __align__(16) short Ks[64 * 64];
    __shared__ __align__(16) short Vt[64 * 64];
    __shared__ __align__(16) short Ps[4][16 * 64];

    const int qr = min(qt * 64 + wv * 16 + l15, Npb - 1);
    const bf16* qp = qkv + (tokbase + qr) * 2304 + h * 64;
    const bf16x8 qf0 = *(const bf16x8*)(const void*)(qp + q4 * 8);
    const bf16x8 qf1 = *(const bf16x8*)(const void*)(qp + 32 + q4 * 8);

    f32x4 Oa[4] = {};
    float mrow[4], lrow[4];
    #pragma unroll
    for (int i = 0; i < 4; i++) { mrow[i] = -1e30f; lrow[i] = 0.f; }

    for (int kv = 0; kv < nkv; kv++) {
        const int kv0 = kv * 64;
        __syncthreads();
        #pragma unroll
        for (int inst = 0; inst < 2; inst++) {
            const int s = inst * 256 + tid;
            const int row = s >> 3, pos = s & 7;
            const int c = pos ^ (row & 7);
            const int krc = min(kv0 + row, Npb - 1);
            GLD_LDS16(qkv + (tokbase + krc) * 2304 + DMODEL + h * 64 + c * 8, &Ks[s * 8]);
        }
        {
            const int r = tid >> 2;
            const int f0 = (tid & 3) * 16;
            const int krc = min(kv0 + r, Npb - 1);
            const short* vp = (const short*)(qkv + (tokbase + krc) * 2304 + 2 * DMODEL + h * 64 + f0);
            short vb[16];
            *(uint4*)&vb[0] = *(const uint4*)vp;
            *(uint4*)&vb[8] = *(const uint4*)(vp + 8);
            const int chunk = r >> 3, r7 = r & 7;
            #pragma unroll
            for (int j = 0; j < 16; j++) {
                const int feat = f0 + j;
                Vt[feat * 64 + (chunk ^ (feat & 7)) * 8 + r7] = vb[j];
            }
        }
        __syncthreads();

        f32x4 s4[4] = {};
        #pragma unroll
        for (int kk = 0; kk < 2; kk++) {
            const bf16x8 qf = kk ? qf1 : qf0;
            const int c = kk * 4 + q4;
            #pragma unroll
            for (int g = 0; g < 4; g++) {
                const int r = g * 16 + l15;
                const bf16x8 kf = *(const bf16x8*)(const void*)&Ks[r * 64 + (c ^ (r & 7)) * 8];
                s4[g] = __builtin_amdgcn_mfma_f32_16x16x32_bf16(qf, kf, s4[g], 0, 0, 0);
            }
        }
        float tmax[4];
        #pragma unroll
        for (int i = 0; i < 4; i++) tmax[i] = -1e30f;
        #pragma unroll
        for (int g = 0; g < 4; g++) {
            const bool valid = (kv0 + g * 16 + l15) < Npb;
            #pragma unroll
            for (int i = 0; i < 4; i++) {
                const float v = s4[g][i] * 0.125f;
                s4[g][i] = valid ? v : -1e30f;
                tmax[i] = fmaxf(tmax[i], s4[g][i]);
            }
        }
        #pragma unroll
        for (int off = 1; off < 16; off <<= 1)
            #pragma unroll
            for (int i = 0; i < 4; i++) tmax[i] = fmaxf(tmax[i], __shfl_xor(tmax[i], off));
        float alpha[4], rsum[4];
        #pragma unroll
        for (int i = 0; i < 4; i++) {
            const float mn = fmaxf(mrow[i], tmax[i]);
            alpha[i] = __expf(mrow[i] - mn);
            mrow[i] = mn;
            rsum[i] = 0.f;
        }
        #pragma unroll
        for (int g = 0; g < 4; g++) {
            const int cc = g * 16 + l15;
            const int chunk = cc >> 3;
            #pragma unroll
            for (int i = 0; i < 4; i++) {
                const int r = q4 * 4 + i;
                const float p = __expf(s4[g][i] - mrow[i]);
                rsum[i] += p;
                Ps[wv][r * 64 + (chunk ^ (r & 7)) * 8 + (cc & 7)] = (short)f2bf_bits(p);
            }
        }
        #pragma unroll
        for (int off = 1; off < 16; off <<= 1)
            #pragma unroll
            for (int i = 0; i < 4; i++) rsum[i] += __shfl_xor(rsum[i], off);
        #pragma unroll
        for (int i = 0; i < 4; i++) lrow[i] = lrow[i] * alpha[i] + rsum[i];
        #pragma unroll
        for (int g = 0; g < 4; g++)
            #pragma unroll
            for (int i = 0; i < 4; i++) Oa[g][i] *= alpha[i];

        #pragma unroll
        for (int kk = 0; kk < 2; kk++) {
            const int c = kk * 4 + q4;
            const bf16x8 pf = *(const bf16x8*)(const void*)&Ps[wv][l15 * 64 + (c ^ (l15 & 7)) * 8];
            #pragma unroll
            for (int g = 0; g < 4; g++) {
                const int feat = g * 16 + l15;
                const bf16x8 vf = *(const bf16x8*)(const void*)&Vt[feat * 64 + (c ^ (feat & 7)) * 8];
                Oa[g] = __builtin_amdgcn_mfma_f32_16x16x32_bf16(pf, vf, Oa[g], 0, 0, 0);
            }
        }
    }

    float inv[4];
    #pragma unroll
    for (int i = 0; i < 4; i++) inv[i] = 1.0f / lrow[i];
    #pragma unroll
    for (int g = 0; g < 4; g++) {
        const int colo = h * 64 + g * 16 + l15;
        #pragma unroll
        for (int i = 0; i < 4; i++) {
            const int rowg = qt * 64 + wv * 16 + q4 * 4 + i;
            if (rowg < Npb)
                o[(tokbase + rowg) * DMODEL + colo] = __float2bfloat16(Oa[g][i] * inv[i]);
        }
    }
}

// ---------------------------------------------------------------------------
// MFMA GEMM: C[M,N] = epi(A[M,K] @ W[N,K]^T [+ bias]). BK=64.
// grid: x = M-tiles (padded to x8, XCD-aligned), y = N-tiles (TN=128).
// TM: 128 (waves 2x2 of 64x64) or 64 (waves 1x4, 64x32 each).
// FD (fuse-down): cols >= N-64 use Wd/biasd/quickGELU -> Cd[.,64];
//                 main cols use gelu -> C with ld = N-64.
// ---------------------------------------------------------------------------
template<int TM, int ACT, bool RES, bool SCALE, bool FD, typename TW>
static __device__ __forceinline__ void gemm_body(
    const bf16* __restrict__ A, const TW* __restrict__ W, const TW* __restrict__ Wd,
    const TW* __restrict__ bias, const TW* __restrict__ biasd,
    const bf16* __restrict__ resid, const TW* __restrict__ scale_p,
    void* __restrict__ C, bf16* __restrict__ Cd,
    bool cf32, int row_off, int M, int N, int K, short* As, short* Bs)
{
    const int tid = threadIdx.x;
    const int lane = tid & 63;
    const int wv = tid >> 6;
    const int l15 = lane & 15, q4 = lane >> 4;
    const int m0 = blockIdx.x * TM, n0 = blockIdx.y * 128;
    const int N1 = FD ? N - ADIM : N;   // main-out width / ld
    constexpr int NF = (TM == 128) ? 4 : 2;
    const int wm = (TM == 128) ? (wv & 1) * 64 : 0;
    const int wn = (TM == 128) ? (wv >> 1) * 64 : wv * 32;

    f32x4 acc[4][NF] = {};

    for (int k0 = 0; k0 < K; k0 += 64) {
        __syncthreads();
        // stage A tile [TM x 64], chunk c stored at slot c^(row&7)
        constexpr int AIT = TM * 8 / 256;
        #pragma unroll
        for (int it = 0; it < AIT; it++) {
            const int i = it * 256 + tid;
            const int row = i >> 3, pos = i & 7;
            const int c = pos ^ (row & 7);
            const int ra = min(m0 + row, M - 1);
            GLD_LDS16(A + (size_t)ra * K + k0 + c * 8, &As[i * 8]);
        }
        // stage W tile [128 x 64]
        #pragma unroll
        for (int it = 0; it < 4; it++) {
            const int i = it * 256 + tid;
            const int row = i >> 3, pos = i & 7;
            const int c = pos ^ (row & 7);
            const int rb = min(n0 + row, N - 1);
            const TW* wp = (FD && rb >= N1) ? Wd + (size_t)(rb - N1) * K
                                            : W + (size_t)rb * K;
            if constexpr (sizeof(TW) == 2) {
                GLD_LDS16(wp + k0 + c * 8, &Bs[i * 8]);
            } else {
                const float* fp = (const float*)wp + k0 + c * 8;
                const float4 w0 = *(const float4*)fp;
                const float4 w1 = *(const float4*)(fp + 4);
                unsigned short hb[8];
                hb[0] = f2bf_bits(w0.x); hb[1] = f2bf_bits(w0.y);
                hb[2] = f2bf_bits(w0.z); hb[3] = f2bf_bits(w0.w);
                hb[4] = f2bf_bits(w1.x); hb[5] = f2bf_bits(w1.y);
                hb[6] = f2bf_bits(w1.z); hb[7] = f2bf_bits(w1.w);
                *(uint4*)&Bs[i * 8] = *(const uint4*)hb;
            }
        }
        __syncthreads();

        #pragma unroll
        for (int kk = 0; kk < 2; kk++) {
            bf16x8 af[4], bfr[NF];
            #pragma unroll
            for (int f = 0; f < 4; f++) {
                const int r = wm + f * 16 + l15;
                af[f] = *(const bf16x8*)(const void*)&As[(r * 8 + ((kk * 4 + q4) ^ (r & 7))) * 8];
            }
            #pragma unroll
            for (int g = 0; g < NF; g++) {
                const int rn = wn + g * 16 + l15;
                bfr[g] = *(const bf16x8*)(const void*)&Bs[(rn * 8 + ((kk * 4 + q4) ^ (rn & 7))) * 8];
            }
            #pragma unroll
            for (int f = 0; f < 4; f++)
                #pragma unroll
                for (int g = 0; g < NF; g++)
                    acc[f][g] = __builtin_amdgcn_mfma_f32_16x16x32_bf16(af[f], bfr[g], acc[f][g], 0, 0, 0);
        }
    }

    const float sc = SCALE ? ld1(scale_p) : 1.0f;
    #pragma unroll
    for (int g = 0; g < NF; g++) {
        const int colg = n0 + wn + g * 16 + l15;
        if (colg >= N) continue;
        const bool isdown = FD && (colg >= N1);
        const float bv = bias ? (isdown ? ld1(biasd + colg - N1) : ld1(bias + colg)) : 0.f;
        #pragma unroll
        for (int f = 0; f < 4; f++) {
            const int rowb = m0 + wm + f * 16 + q4 * 4;
            #pragma unroll
            for (int i = 0; i < 4; i++) {
                const int rowg = rowb + i;
                if (rowg >= M) continue;
                float v = acc[f][g][i] + bv;
                if (FD) {
                    if (isdown) v = v / (1.0f + __expf(-1.702f * v));
                    else v = 0.5f * v * (1.0f + erff(v * 0.70710678118654752f));
                } else if (ACT == 1) v = 0.5f * v * (1.0f + erff(v * 0.70710678118654752f));
                else if (ACT == 2) v = v / (1.0f + __expf(-1.702f * v));
                if (SCALE) v *= sc;
                if (RES) v += bf2f(resid[(size_t)rowg * N + colg]);
                if (FD && isdown) {
                    Cd[(size_t)rowg * ADIM + (colg - N1)] = __float2bfloat16(v);
                } else {
                    const size_t sidx = (size_t)(rowg + row_off) * N1 + colg;
                    if (cf32) ((float*)C)[sidx] = v;
                    else ((bf16*)C)[sidx] = __float2bfloat16(v);
                }
            }
        }
    }
}

// out_mode: 0 bf16, 1 f32 iff inputs f32, 2 f32
template<int TM, int ACT, bool RES, bool SCALE, bool FD>
__global__ __launch_bounds__(256)
void mfma_gemm_kernel(const int* __restrict__ flag, const bf16* __restrict__ A,
                      const void* __restrict__ W, const void* __restrict__ Wd,
                      const void* __restrict__ bias, const void* __restrict__ biasd,
                      const bf16* __restrict__ resid, const void* __restrict__ sp,
                      void* __restrict__ C, bf16* __restrict__ Cd,
                      int out_mode, int row_off, int M, int N, int K)
{
    __shared__ __align__(16) short As[TM * 64];
    __shared__ __align__(16) short Bs[128 * 64];
    if (blockIdx.x * TM >= M) return;   // padded XCD-alignment blocks
    const bool cf32 = (out_mode == 2) || (out_mode == 1 && flag[0] != 0);
    if (flag[0])
        gemm_body<TM, ACT, RES, SCALE, FD, float>(A, (const float*)W, (const float*)Wd,
            (const float*)bias, (const float*)biasd, resid, (const float*)sp, C, Cd,
            cf32, row_off, M, N, K, As, Bs);
    else
        gemm_body<TM, ACT, RES, SCALE, FD, bf16>(A, (const bf16*)W, (const bf16*)Wd,
            (const bf16*)bias, (const bf16*)biasd, resid, (const bf16*)sp, C, Cd,
            cf32, row_off, M, N, K, As, Bs);
}

// ---------------------------------------------------------------------------
// Host orchestration
// ---------------------------------------------------------------------------
struct SW {
    const void *ln1_g, *ln1_b, *qkv_w, *qkv_b, *proj_w, *proj_b,
               *ln2_g, *ln2_b, *fc1_w, *fc1_b, *fc2_w, *fc2_b,
               *down_w, *down_b, *up_w, *up_b, *scale;
};

static void run_stream(const int* flag, bf16* t0, int M, int Npb, int nb, const SW& w,
                       bf16* h, bf16* big, bf16* ah, void* out, int out_row_off,
                       bool skip_ln1, hipStream_t s)
{
    const int mt128 = pad8((M + 127) / 128);
    const int mt64  = pad8((M + 63) / 64);
    const dim3 gqkv(mt128, 18);           // N=2304
    const dim3 gfc1(mt128, 25);           // N=3136 (fc1 + down fused)
    const dim3 g768(mt64, 6);             // N=768 trio

    if (!skip_ln1) ln_kernel<<<M, 256, 0, s>>>(flag, t0, w.ln1_g, w.ln1_b, h);
    mfma_gemm_kernel<128, 0, false, false, false><<<gqkv, 256, 0, s>>>(
        flag, h, w.qkv_w, nullptr, w.qkv_b, nullptr, nullptr, nullptr, big, nullptr,
        0, 0, M, 2304, DMODEL);
    flash_attn_kernel<<<dim3(nb * H_HEADS, (Npb + 63) / 64), 256, 0, s>>>(big, h, Npb);
    mfma_gemm_kernel<64, 0, true, false, false><<<g768, 256, 0, s>>>(
        flag, h, w.proj_w, nullptr, w.proj_b, nullptr, t0, nullptr, t0, nullptr,
        0, 0, M, DMODEL, DMODEL);
    ln_kernel<<<M, 256, 0, s>>>(flag, t0, w.ln2_g, w.ln2_b, h);
    // fc1(gelu) + down(quickgelu) fused: N = 3072 + 64
    mfma_gemm_kernel<128, 1, false, false, true><<<gfc1, 256, 0, s>>>(
        flag, h, w.fc1_w, w.down_w, w.fc1_b, w.down_b, nullptr, nullptr, big, ah,
        0, 0, M, DFF + ADIM, DMODEL);
    mfma_gemm_kernel<64, 0, true, false, false><<<g768, 256, 0, s>>>(
        flag, big, w.fc2_w, nullptr, w.fc2_b, nullptr, t0, nullptr, t0, nullptr,
        0, 0, M, DMODEL, DFF);
    mfma_gemm_kernel<64, 0, true, true, false><<<g768, 256, 0, s>>>(
        flag, ah, w.up_w, nullptr, w.up_b, nullptr, t0, w.scale, out, nullptr,
        1, out_row_off, M, DMODEL, ADIM);
}

extern "C" void kernel_launch(void* const* d_in, const int* in_sizes, int n_in,
                              void* d_out, int out_size, void* d_ws, size_t ws_size,
                              hipStream_t stream)
{
    SW sw, rw;
    auto fill = [&](SW& s, int base) {
        s.ln1_g = d_in[base + 0];  s.ln1_b = d_in[base + 1];
        s.qkv_w = d_in[base + 2];  s.qkv_b = d_in[base + 3];
        s.proj_w = d_in[base + 4]; s.proj_b = d_in[base + 5];
        s.ln2_g = d_in[base + 6];  s.ln2_b = d_in[base + 7];
        s.fc1_w = d_in[base + 8];  s.fc1_b = d_in[base + 9];
        s.fc2_w = d_in[base + 10]; s.fc2_b = d_in[base + 11];
        s.down_w = d_in[base + 12]; s.down_b = d_in[base + 13];
        s.up_w = d_in[base + 14];  s.up_b = d_in[base + 15];
        s.scale = d_in[base + 16];
    };
    fill(sw, 5);
    fill(rw, 22);

    const int Mx = BATCH * NA;   // 8192
    const int My = BATCH * NV;   // 3136

    int* flag = (int*)d_ws;
    char* base = (char*)d_ws + 256;
    bf16* x1 = (bf16*)base;                base += (size_t)Mx * DMODEL * 2;
    bf16* y1 = (bf16*)base;                base += (size_t)My * DMODEL * 2;
    bf16* fused = (bf16*)base;             base += (size_t)BATCH * NLAT * DMODEL * 2;
    char* un = base;  // union: fusion scratch, then stream buffers

    // fusion scratch in union
    bf16* Cc = (bf16*)un;
    bf16* Lb = (bf16*)(un + (size_t)MCAT * DMODEL * 2);
    float* scores = (float*)(un + (size_t)(MCAT + 64) * DMODEL * 2);
    float* P = (float*)((char*)scores + (size_t)MCAT * NLAT * 4 + 256);

    // stream buffers in union
    const size_t stream_need_big = ((size_t)Mx * DMODEL + (size_t)Mx * DFF + (size_t)Mx * ADIM) * 2;
    const size_t fixed = 256 + ((size_t)Mx * DMODEL + (size_t)My * DMODEL + (size_t)BATCH * NLAT * DMODEL) * 2;
    const bool big_ws = ws_size >= fixed + stream_need_big;
    const int hrows = big_ws ? Mx : My;
    bf16* h  = (bf16*)un;
    bf16* big = h + (size_t)hrows * DMODEL;
    bf16* ah = big + (size_t)hrows * DFF;

    detect_dtype_kernel<<<1, 64, 0, stream>>>((const unsigned short*)d_in[0], flag);

    // --- fusion: pack -> scores GEMM -> softmax -> weighted sum ---
    pack_concat_kernel<<<MCAT + NLAT, 256, 0, stream>>>(flag, d_in[0], d_in[1], d_in[2], Cc, Lb);
    mfma_gemm_kernel<128, 0, false, false, false><<<dim3(pad8((MCAT + 127) / 128), 1), 256, 0, stream>>>(
        flag + 1, Cc, Lb, nullptr, nullptr, nullptr, nullptr, nullptr, scores, nullptr,
        2, 0, MCAT, NLAT, DMODEL);
    fusion_softmax_kernel<<<BATCH * NLAT, 64, 0, stream>>>(scores, P);
    fusion_wsum_kernel<<<dim3(DMODEL / 128, BATCH), 256, 0, stream>>>(Cc, P, fused);

    // --- x stream (attend_fused writes h=LN1(x1) when unchunked) ---
    attend_fused_kernel<<<BATCH * NA, 256, 0, stream>>>(
        flag, d_in[0], fused, d_in[3], sw.ln1_g, sw.ln1_b, x1, big_ws ? h : nullptr, NA);
    if (big_ws) {
        run_stream(flag, x1, Mx, NA, BATCH, sw, h, big, ah, d_out, 0, true, stream);
    } else {
        const int MCH = 2048;
        for (int c = 0; c < Mx / MCH; c++)
            run_stream(flag, x1 + (size_t)c * MCH * DMODEL, MCH, NA, MCH / NA, sw,
                       h, big, ah, d_out, c * MCH, false, stream);
    }

    // --- y stream (runs after x so h reuse is safe; always fused LN1) ---
    attend_fused_kernel<<<BATCH * NV, 256, 0, stream>>>(
        flag, d_in[1], fused, d_in[4], rw.ln1_g, rw.ln1_b, y1, h, NV);
    run_stream(flag, y1, My, NV, BATCH, rw, h, big, ah, d_out, Mx, true, stream);
}

// Round 6
// 1204.968 us; speedup vs baseline: 1.1192x; 1.1192x over previous
//
#include <hip/hip_runtime.h>
#include <hip/hip_bf16.h>

// AdaptFormer — Round 5:
//  * LDS-transpose GEMM epilogue: acc -> swizzled 32KB LDS (f32) -> coalesced
//    f32x4 reads -> b64/b128 stores. Replaces 64 scalar 2-byte stores/thread
//    (R4's 1.7x write-amp + issue-bound epilogue at short K).
//  * x/y streams merged into single GEMM launches (M=11328, per-M-tile weight
//    select; 8192 boundary is tile-aligned) -> ~15 launches, no tail waste,
//    up-GEMM writes d_out directly.

#define H_HEADS 12
#define DMODEL 768
#define DFF 3072
#define ADIM 64
#define NLAT 32
#define BATCH 16
#define NA 512
#define NV 196
#define NTOT 708
#define MCAT (BATCH * NTOT)   // 11328
#define MTOT (BATCH * (NA + NV))  // 11328

typedef __hip_bfloat16 bf16;
using bf16x8 = __attribute__((ext_vector_type(8))) short;
using f32x4  = __attribute__((ext_vector_type(4))) float;

static __device__ __forceinline__ float bf2f(bf16 v) { return __bfloat162float(v); }
static __device__ __forceinline__ float bflo(unsigned u) { return __uint_as_float(u << 16); }
static __device__ __forceinline__ float ld1(const float* p) { return *p; }
static __device__ __forceinline__ float ld1(const bf16* p) { return bf2f(*p); }
static __device__ __forceinline__ unsigned short f2bf_bits(float v) {
    unsigned u = __float_as_uint(v);
    return (unsigned short)((u + 0x7fffu + ((u >> 16) & 1u)) >> 16);
}

#define GLD_LDS16(gp, lp) __builtin_amdgcn_global_load_lds( \
    (const __attribute__((address_space(1))) void*)(gp), \
    (__attribute__((address_space(3))) void*)(lp), 16, 0, 0)

static inline int pad8(int v) { return (v + 7) & ~7; }

// ---------------------------------------------------------------------------
__global__ void detect_dtype_kernel(const unsigned short* __restrict__ x, int* __restrict__ flag)
{
    if (threadIdx.x == 0 && blockIdx.x == 0) {
        int big = 0;
        for (int i = 0; i < 2048; i++) {
            unsigned e = (x[i] >> 7) & 0xFF;
            if (e >= 0x90) big++;
        }
        flag[0] = (big > 16) ? 1 : 0;
        flag[1] = 0;
    }
}

// ---------------------------------------------------------------------------
// Pack concat -> Cc bf16 [MCAT,768]; latents -> Lb bf16 [32,768]
// ---------------------------------------------------------------------------
template<typename TIn>
static __device__ __forceinline__ void pack_body(
    const TIn* __restrict__ x, const TIn* __restrict__ y, const TIn* __restrict__ lat,
    bf16* __restrict__ Cc, bf16* __restrict__ Lb)
{
    const int r = blockIdx.x, tid = threadIdx.x;
    const TIn* src;
    bf16* dst;
    if (r < MCAT) {
        const int b = r / NTOT, n = r - b * NTOT;
        src = (n < NA) ? x + ((size_t)(b * NA + n)) * DMODEL
                       : y + ((size_t)(b * NV + (n - NA))) * DMODEL;
        dst = Cc + (size_t)r * DMODEL;
    } else {
        src = lat + (size_t)(r - MCAT) * DMODEL;
        dst = Lb + (size_t)(r - MCAT) * DMODEL;
    }
    dst[tid]       = __float2bfloat16(ld1(src + tid));
    dst[tid + 256] = __float2bfloat16(ld1(src + tid + 256));
    dst[tid + 512] = __float2bfloat16(ld1(src + tid + 512));
}

__global__ __launch_bounds__(256)
void pack_concat_kernel(const int* __restrict__ flag, const void* x, const void* y,
                        const void* lat, bf16* __restrict__ Cc, bf16* __restrict__ Lb)
{
    if (flag[0]) pack_body<float>((const float*)x, (const float*)y, (const float*)lat, Cc, Lb);
    else         pack_body<bf16>((const bf16*)x, (const bf16*)y, (const bf16*)lat, Cc, Lb);
}

// ---------------------------------------------------------------------------
// Fusion softmax: P[b][l][n] over n=708, rows zero-padded to 768
// ---------------------------------------------------------------------------
__global__ __launch_bounds__(64)
void fusion_softmax_kernel(const float* __restrict__ scores, float* __restrict__ P)
{
    const int b = blockIdx.x >> 5, l = blockIdx.x & 31, lane = threadIdx.x;
    const float* sp = scores + (size_t)b * NTOT * NLAT + l;
    float v[12];
    float mx = -1e30f;
    #pragma unroll
    for (int i = 0; i < 12; i++) {
        const int n = lane + i * 64;
        v[i] = (n < NTOT) ? sp[(size_t)n * NLAT] * 0.03608439182435161f : -1e30f;
        mx = fmaxf(mx, v[i]);
    }
    #pragma unroll
    for (int off = 32; off; off >>= 1) mx = fmaxf(mx, __shfl_xor(mx, off));
    float den = 0.f;
    #pragma unroll
    for (int i = 0; i < 12; i++) { v[i] = __expf(v[i] - mx); den += v[i]; }
    #pragma unroll
    for (int off = 32; off; off >>= 1) den += __shfl_xor(den, off);
    const float inv = 1.0f / den;
    float* op = P + ((size_t)b * NLAT + l) * 768;
    #pragma unroll
    for (int i = 0; i < 12; i++) {
        const int n = lane + i * 64;
        op[n] = (n < NTOT) ? v[i] * inv : 0.f;
    }
}

// ---------------------------------------------------------------------------
// Weighted sum: fused[b][l][d] = sum_n P[b][l][n] * Cc[b*708+n][d]
// ---------------------------------------------------------------------------
__global__ __launch_bounds__(256)
void fusion_wsum_kernel(const bf16* __restrict__ Cc, const float* __restrict__ P,
                        bf16* __restrict__ fused)
{
    const int b = blockIdx.y, d0 = blockIdx.x * 128;
    const int tid = threadIdx.x;
    const int lg = tid >> 5, dg = tid & 31;
    const int l0 = lg * 4;

    __shared__ float Ct[64][132];
    __shared__ float Ps[32][68];

    float acc[4][4] = {};

    for (int nc = 0; nc < 12; nc++) {
        const int n0 = nc * 64;
        __syncthreads();
        #pragma unroll
        for (int it = 0; it < 8; it++) {
            const int idx = it * 1024 + tid * 4;
            const int r = idx >> 7, c = idx & 127;
            const int gn = n0 + r;
            float4 v = make_float4(0.f, 0.f, 0.f, 0.f);
            if (gn < NTOT) {
                const ushort4 u = *(const ushort4*)(Cc + ((size_t)(b * NTOT + gn)) * DMODEL + d0 + c);
                v = make_float4(bflo(u.x), bflo(u.y), bflo(u.z), bflo(u.w));
            }
            Ct[r][c] = v.x; Ct[r][c + 1] = v.y; Ct[r][c + 2] = v.z; Ct[r][c + 3] = v.w;
        }
        {
            const int l = tid >> 3, off = (tid & 7) * 8;
            const float* pp = P + ((size_t)b * NLAT + l) * 768 + n0 + off;
            const float4 p0 = *(const float4*)pp;
            const float4 p1 = *(const float4*)(pp + 4);
            Ps[l][off] = p0.x; Ps[l][off + 1] = p0.y; Ps[l][off + 2] = p0.z; Ps[l][off + 3] = p0.w;
            Ps[l][off + 4] = p1.x; Ps[l][off + 5] = p1.y; Ps[l][off + 6] = p1.z; Ps[l][off + 7] = p1.w;
        }
        __syncthreads();

        for (int n = 0; n < 64; n++) {
            const float4 v = *(const float4*)&Ct[n][dg * 4];
            #pragma unroll
            for (int i = 0; i < 4; i++) {
                const float p = Ps[l0 + i][n];
                acc[i][0] += p * v.x; acc[i][1] += p * v.y;
                acc[i][2] += p * v.z; acc[i][3] += p * v.w;
            }
        }
    }

    #pragma unroll
    for (int i = 0; i < 4; i++) {
        bf16* op = fused + ((size_t)b * NLAT + l0 + i) * DMODEL + d0 + dg * 4;
        #pragma unroll
        for (int j = 0; j < 4; j++) op[j] = __float2bfloat16(acc[i][j]);
    }
}

// ---------------------------------------------------------------------------
// Fusion stage 2 (+ optional fused LN1)
// ---------------------------------------------------------------------------
template<typename TIn>
static __device__ __forceinline__ void attend_fused_body(
    const TIn* __restrict__ t, const bf16* __restrict__ fused,
    const TIn* __restrict__ scale_p, const TIn* __restrict__ lng, const TIn* __restrict__ lnb,
    bf16* __restrict__ out, bf16* __restrict__ hout, int Npb)
{
    const int tid = threadIdx.x;
    const int gid = blockIdx.x;
    const int b = gid / Npb;
    const TIn* row = t + (size_t)gid * DMODEL;
    const bf16* fb = fused + (size_t)b * NLAT * DMODEL;

    __shared__ float q[DMODEL];
    __shared__ float p[NLAT];
    __shared__ float rs[4], rq[4];

    for (int d = tid; d < DMODEL; d += 256) q[d] = ld1(row + d);
    __syncthreads();

    const int g = tid >> 3, li = tid & 7;
    float s = 0.f;
    const bf16* fr = fb + (size_t)g * DMODEL;
    for (int d = li; d < DMODEL; d += 8) s += q[d] * bf2f(fr[d]);
    s += __shfl_xor(s, 1); s += __shfl_xor(s, 2); s += __shfl_xor(s, 4);
    if (li == 0) p[g] = s * 0.03608439182435161f;
    __syncthreads();

    float mx = -1e30f;
    #pragma unroll
    for (int l = 0; l < NLAT; l++) mx = fmaxf(mx, p[l]);
    float w[NLAT];
    float den = 0.f;
    #pragma unroll
    for (int l = 0; l < NLAT; l++) { w[l] = __expf(p[l] - mx); den += w[l]; }
    const float sA = ld1(scale_p) / den;

    float a0 = 0.f, a1 = 0.f, a2 = 0.f;
    #pragma unroll
    for (int l = 0; l < NLAT; l++) {
        const bf16* fv = fb + (size_t)l * DMODEL;
        a0 += w[l] * bf2f(fv[tid]);
        a1 += w[l] * bf2f(fv[tid + 256]);
        a2 += w[l] * bf2f(fv[tid + 512]);
    }
    const float t0v = q[tid] + sA * a0;
    const float t1v = q[tid + 256] + sA * a1;
    const float t2v = q[tid + 512] + sA * a2;
    bf16* o = out + (size_t)gid * DMODEL;
    o[tid]       = __float2bfloat16(t0v);
    o[tid + 256] = __float2bfloat16(t1v);
    o[tid + 512] = __float2bfloat16(t2v);

    if (hout) {
        float ss = t0v + t1v + t2v;
        float sq = t0v * t0v + t1v * t1v + t2v * t2v;
        #pragma unroll
        for (int off = 32; off; off >>= 1) { ss += __shfl_xor(ss, off); sq += __shfl_xor(sq, off); }
        if ((tid & 63) == 0) { rs[tid >> 6] = ss; rq[tid >> 6] = sq; }
        __syncthreads();
        ss = rs[0] + rs[1] + rs[2] + rs[3];
        sq = rq[0] + rq[1] + rq[2] + rq[3];
        const float mean = ss * (1.0f / DMODEL);
        const float var = sq * (1.0f / DMODEL) - mean * mean;
        const float r = rsqrtf(var + 1e-6f);
        bf16* ho = hout + (size_t)gid * DMODEL;
        ho[tid]       = __float2bfloat16((t0v - mean) * r * ld1(lng + tid)       + ld1(lnb + tid));
        ho[tid + 256] = __float2bfloat16((t1v - mean) * r * ld1(lng + tid + 256) + ld1(lnb + tid + 256));
        ho[tid + 512] = __float2bfloat16((t2v - mean) * r * ld1(lng + tid + 512) + ld1(lnb + tid + 512));
    }
}

__global__ __launch_bounds__(256)
void attend_fused_kernel(const int* __restrict__ flag, const void* t, const bf16* __restrict__ fused,
                         const void* scale_p, const void* lng, const void* lnb,
                         bf16* __restrict__ out, bf16* __restrict__ hout, int Npb)
{
    if (flag[0]) attend_fused_body<float>((const float*)t, fused, (const float*)scale_p,
                                          (const float*)lng, (const float*)lnb, out, hout, Npb);
    else         attend_fused_body<bf16>((const bf16*)t, fused, (const bf16*)scale_p,
                                         (const bf16*)lng, (const bf16*)lnb, out, hout, Npb);
}

// ---------------------------------------------------------------------------
// LayerNorm, dual-stream gamma/beta select by row < split
// ---------------------------------------------------------------------------
template<typename TW>
static __device__ __forceinline__ void ln_body(
    const bf16* __restrict__ in, const TW* __restrict__ g,
    const TW* __restrict__ bta, bf16* __restrict__ out)
{
    const int tid = threadIdx.x;
    const bf16* p = in + (size_t)blockIdx.x * DMODEL;
    const float v0 = bf2f(p[tid]), v1 = bf2f(p[tid + 256]), v2 = bf2f(p[tid + 512]);
    float s = v0 + v1 + v2;
    float sq = v0 * v0 + v1 * v1 + v2 * v2;
    #pragma unroll
    for (int off = 32; off; off >>= 1) { s += __shfl_xor(s, off); sq += __shfl_xor(sq, off); }
    __shared__ float rs[4], rq[4];
    if ((tid & 63) == 0) { rs[tid >> 6] = s; rq[tid >> 6] = sq; }
    __syncthreads();
    s = rs[0] + rs[1] + rs[2] + rs[3];
    sq = rq[0] + rq[1] + rq[2] + rq[3];
    const float mean = s * (1.0f / DMODEL);
    const float var = sq * (1.0f / DMODEL) - mean * mean;
    const float r = rsqrtf(var + 1e-6f);
    bf16* o = out + (size_t)blockIdx.x * DMODEL;
    o[tid]       = __float2bfloat16((v0 - mean) * r * ld1(g + tid)       + ld1(bta + tid));
    o[tid + 256] = __float2bfloat16((v1 - mean) * r * ld1(g + tid + 256) + ld1(bta + tid + 256));
    o[tid + 512] = __float2bfloat16((v2 - mean) * r * ld1(g + tid + 512) + ld1(bta + tid + 512));
}

__global__ __launch_bounds__(256)
void ln_kernel(const int* __restrict__ flag, const bf16* __restrict__ in,
               const void* g0, const void* b0, const void* g1, const void* b1,
               bf16* __restrict__ out, int split)
{
    const bool isY = (int)blockIdx.x >= split;
    const void* g = isY ? g1 : g0;
    const void* b = isY ? b1 : b0;
    if (flag[0]) ln_body<float>(in, (const float*)g, (const float*)b, out);
    else         ln_body<bf16>(in, (const bf16*)g, (const bf16*)b, out);
}

// ---------------------------------------------------------------------------
// Flash MFMA attention (verified). grid: (bh major, qt).
// ---------------------------------------------------------------------------
__global__ __launch_bounds__(256)
void flash_attn_kernel(const bf16* __restrict__ qkv, bf16* __restrict__ o, int Npb)
{
    const int tid = threadIdx.x;
    const int wv = tid >> 6, lane = tid & 63;
    const int l15 = lane & 15, q4 = lane >> 4;
    const int h = blockIdx.x % H_HEADS, bb = blockIdx.x / H_HEADS;
    const int qt = blockIdx.y;
    const int nkv = (Npb + 63) >> 6;
    const size_t tokbase = (size_t)bb * Npb;

    __shared__ __align__(16) short Ks[64 * 64];
    __shared__ __align__(16) short Vt[64 * 64];
    __shared__ __align__(16) short Ps[4][16 * 64];

    const int qr = min(qt * 64 + wv * 16 + l15, Npb - 1);
    const bf16* qp = qkv + (tokbase + qr) * 2304 + h * 64;
    const bf16x8 qf0 = *(const bf16x8*)(const void*)(qp + q4 * 8);
    const bf16x8 qf1 = *(const bf16x8*)(const void*)(qp + 32 + q4 * 8);

    f32x4 Oa[4] = {};
    float mrow[4], lrow[4];
    #pragma unroll
    for (int i = 0; i < 4; i++) { mrow[i] = -1e30f; lrow[i] = 0.f; }

    for (int kv = 0; kv < nkv; kv++) {
        const int kv0 = kv * 64;
        __syncthreads();
        #pragma unroll
        for (int inst = 0; inst < 2; inst++) {
            const int s = inst * 256 + tid;
            const int row = s >> 3, pos = s & 7;
            const int c = pos ^ (row & 7);
            const int krc = min(kv0 + row, Npb - 1);
            GLD_LDS16(qkv + (tokbase + krc) * 2304 + DMODEL + h * 64 + c * 8, &Ks[s * 8]);
        }
        {
            const int r = tid >> 2;
            const int f0 = (tid & 3) * 16;
            const int krc = min(kv0 + r, Npb - 1);
            const short* vp = (const short*)(qkv + (tokbase + krc) * 2304 + 2 * DMODEL + h * 64 + f0);
            short vb[16];
            *(uint4*)&vb[0] = *(const uint4*)vp;
            *(uint4*)&vb[8] = *(const uint4*)(vp + 8);
            const int chunk = r >> 3, r7 = r & 7;
            #pragma unroll
            for (int j = 0; j < 16; j++) {
                const int feat = f0 + j;
                Vt[feat * 64 + (chunk ^ (feat & 7)) * 8 + r7] = vb[j];
            }
        }
        __syncthreads();

        f32x4 s4[4] = {};
        #pragma unroll
        for (int kk = 0; kk < 2; kk++) {
            const bf16x8 qf = kk ? qf1 : qf0;
            const int c = kk * 4 + q4;
            #pragma unroll
            for (int g = 0; g < 4; g++) {
                const int r = g * 16 + l15;
                const bf16x8 kf = *(const bf16x8*)(const void*)&Ks[r * 64 + (c ^ (r & 7)) * 8];
                s4[g] = __builtin_amdgcn_mfma_f32_16x16x32_bf16(qf, kf, s4[g], 0, 0, 0);
            }
        }
        float tmax[4];
        #pragma unroll
        for (int i = 0; i < 4; i++) tmax[i] = -1e30f;
        #pragma unroll
        for (int g = 0; g < 4; g++) {
            const bool valid = (kv0 + g * 16 + l15) < Npb;
            #pragma unroll
            for (int i = 0; i < 4; i++) {
                const float v = s4[g][i] * 0.125f;
                s4[g][i] = valid ? v : -1e30f;
                tmax[i] = fmaxf(tmax[i], s4[g][i]);
            }
        }
        #pragma unroll
        for (int off = 1; off < 16; off <<= 1)
            #pragma unroll
            for (int i = 0; i < 4; i++) tmax[i] = fmaxf(tmax[i], __shfl_xor(tmax[i], off));
        float alpha[4], rsum[4];
        #pragma unroll
        for (int i = 0; i < 4; i++) {
            const float mn = fmaxf(mrow[i], tmax[i]);
            alpha[i] = __expf(mrow[i] - mn);
            mrow[i] = mn;
            rsum[i] = 0.f;
        }
        #pragma unroll
        for (int g = 0; g < 4; g++) {
            const int cc = g * 16 + l15;
            const int chunk = cc >> 3;
            #pragma unroll
            for (int i = 0; i < 4; i++) {
                const int r = q4 * 4 + i;
                const float p = __expf(s4[g][i] - mrow[i]);
                rsum[i] += p;
                Ps[wv][r * 64 + (chunk ^ (r & 7)) * 8 + (cc & 7)] = (short)f2bf_bits(p);
            }
        }
        #pragma unroll
        for (int off = 1; off < 16; off <<= 1)
            #pragma unroll
            for (int i = 0; i < 4; i++) rsum[i] += __shfl_xor(rsum[i], off);
        #pragma unroll
        for (int i = 0; i < 4; i++) lrow[i] = lrow[i] * alpha[i] + rsum[i];
        #pragma unroll
        for (int g = 0; g < 4; g++)
            #pragma unroll
            for (int i = 0; i < 4; i++) Oa[g][i] *= alpha[i];

        #pragma unroll
        for (int kk = 0; kk < 2; kk++) {
            const int c = kk * 4 + q4;
            const bf16x8 pf = *(const bf16x8*)(const void*)&Ps[wv][l15 * 64 + (c ^ (l15 & 7)) * 8];
            #pragma unroll
            for (int g = 0; g < 4; g++) {
                const int feat = g * 16 + l15;
                const bf16x8 vf = *(const bf16x8*)(const void*)&Vt[feat * 64 + (c ^ (feat & 7)) * 8];
                Oa[g] = __builtin_amdgcn_mfma_f32_16x16x32_bf16(pf, vf, Oa[g], 0, 0, 0);
            }
        }
    }

    float inv[4];
    #pragma unroll
    for (int i = 0; i < 4; i++) inv[i] = 1.0f / lrow[i];
    #pragma unroll
    for (int g = 0; g < 4; g++) {
        const int colo = h * 64 + g * 16 + l15;
        #pragma unroll
        for (int i = 0; i < 4; i++) {
            const int rowg = qt * 64 + wv * 16 + q4 * 4 + i;
            if (rowg < Npb)
                o[(tokbase + rowg) * DMODEL + colo] = __float2bfloat16(Oa[g][i] * inv[i]);
        }
    }
}

// ---------------------------------------------------------------------------
// MFMA GEMM v2: C[M,N] = epi(A[M,K] @ W[N,K]^T [+ bias]). BK=64.
// Epilogue via swizzled LDS transpose -> coalesced vector stores.
// FD: cols >= N-64 -> Cd (quickGELU), main cols -> C ld N-64 (GELU).
// ---------------------------------------------------------------------------
template<int TM, int ACT, bool RES, bool SCALE, bool FD, typename TW>
static __device__ __forceinline__ void gemm_body(
    const bf16* __restrict__ A, const TW* __restrict__ W, const TW* __restrict__ Wd,
    const TW* __restrict__ bias, const TW* __restrict__ biasd,
    const bf16* __restrict__ resid, const TW* __restrict__ scale_p,
    void* __restrict__ C, bf16* __restrict__ Cd,
    bool cf32, int row_off, int M, int N, int K,
    short* As, short* Bs, float* Ep)
{
    const int tid = threadIdx.x;
    const int lane = tid & 63;
    const int wv = tid >> 6;
    const int l15 = lane & 15, q4 = lane >> 4;
    const int m0 = blockIdx.x * TM, n0 = blockIdx.y * 128;
    const int N1 = FD ? N - ADIM : N;
    constexpr int NF = (TM == 128) ? 4 : 2;
    const int wm = (TM == 128) ? (wv & 1) * 64 : 0;
    const int wn = (TM == 128) ? (wv >> 1) * 64 : wv * 32;

    f32x4 acc[4][NF] = {};

    for (int k0 = 0; k0 < K; k0 += 64) {
        __syncthreads();
        constexpr int AIT = TM * 8 / 256;
        #pragma unroll
        for (int it = 0; it < AIT; it++) {
            const int i = it * 256 + tid;
            const int row = i >> 3, pos = i & 7;
            const int c = pos ^ (row & 7);
            const int ra = min(m0 + row, M - 1);
            GLD_LDS16(A + (size_t)ra * K + k0 + c * 8, &As[i * 8]);
        }
        #pragma unroll
        for (int it = 0; it < 4; it++) {
            const int i = it * 256 + tid;
            const int row = i >> 3, pos = i & 7;
            const int c = pos ^ (row & 7);
            const int rb = min(n0 + row, N - 1);
            const TW* wp = (FD && rb >= N1) ? Wd + (size_t)(rb - N1) * K : W + (size_t)rb * K;
            if constexpr (sizeof(TW) == 2) {
                GLD_LDS16(wp + k0 + c * 8, &Bs[i * 8]);
            } else {
                const float* fp = (const float*)wp + k0 + c * 8;
                const float4 w0 = *(const float4*)fp;
                const float4 w1 = *(const float4*)(fp + 4);
                unsigned short hb[8];
                hb[0] = f2bf_bits(w0.x); hb[1] = f2bf_bits(w0.y);
                hb[2] = f2bf_bits(w0.z); hb[3] = f2bf_bits(w0.w);
                hb[4] = f2bf_bits(w1.x); hb[5] = f2bf_bits(w1.y);
                hb[6] = f2bf_bits(w1.z); hb[7] = f2bf_bits(w1.w);
                *(uint4*)&Bs[i * 8] = *(const uint4*)hb;
            }
        }
        __syncthreads();

        #pragma unroll
        for (int kk = 0; kk < 2; kk++) {
            bf16x8 af[4], bfr[NF];
            #pragma unroll
            for (int f = 0; f < 4; f++) {
                const int r = wm + f * 16 + l15;
                af[f] = *(const bf16x8*)(const void*)&As[(r * 8 + ((kk * 4 + q4) ^ (r & 7))) * 8];
            }
            #pragma unroll
            for (int g = 0; g < NF; g++) {
                const int rn = wn + g * 16 + l15;
                bfr[g] = *(const bf16x8*)(const void*)&Bs[(rn * 8 + ((kk * 4 + q4) ^ (rn & 7))) * 8];
            }
            #pragma unroll
            for (int f = 0; f < 4; f++)
                #pragma unroll
                for (int g = 0; g < NF; g++)
                    acc[f][g] = __builtin_amdgcn_mfma_f32_16x16x32_bf16(af[f], bfr[g], acc[f][g], 0, 0, 0);
        }
    }
    __syncthreads();  // staging LDS now reusable as epilogue tile

    const float sc = SCALE ? ld1(scale_p) : 1.0f;
    constexpr int NPASS = (TM == 128) ? 2 : 1;
    #pragma unroll
    for (int pass = 0; pass < NPASS; pass++) {
        // write phase: waves owning rows [pass*64, pass*64+64) deposit f32
        if (wm == pass * 64) {
            #pragma unroll
            for (int g = 0; g < NF; g++) {
                const int col = wn + g * 16 + l15;           // 0..127
                const int colg = n0 + col;
                const bool isdown = FD && (colg >= N1);
                const float bv = bias ? (isdown ? ld1(biasd + (colg - N1)) : ld1(bias + colg)) : 0.f;
                #pragma unroll
                for (int f = 0; f < 4; f++) {
                    #pragma unroll
                    for (int i = 0; i < 4; i++) {
                        const int row = f * 16 + q4 * 4 + i; // 0..63 pass-local
                        float v = acc[f][g][i] + bv;
                        if (FD) {
                            if (isdown) v = v / (1.0f + __expf(-1.702f * v));
                            else v = 0.5f * v * (1.0f + erff(v * 0.70710678118654752f));
                        } else if (ACT == 1) v = 0.5f * v * (1.0f + erff(v * 0.70710678118654752f));
                        else if (ACT == 2) v = v / (1.0f + __expf(-1.702f * v));
                        if (SCALE) v *= sc;
                        const int c = col >> 2;
                        Ep[row * 128 + (((c ^ (row & 31))) << 2) + (col & 3)] = v;
                    }
                }
            }
        }
        __syncthreads();
        // read/store phase: 256 threads x 8 chunks of 4 cols, coalesced
        #pragma unroll
        for (int it = 0; it < 8; it++) {
            const int cid = it * 256 + tid;
            const int row = cid >> 5, c = cid & 31;
            const int rowg = m0 + pass * 64 + row;
            const int colg = n0 + c * 4;
            if (rowg < M && colg < N) {
                f32x4 v = *(const f32x4*)&Ep[row * 128 + (((c ^ (row & 31))) << 2)];
                if (FD && colg >= N1) {
                    ushort4 u;
                    u.x = f2bf_bits(v[0]); u.y = f2bf_bits(v[1]);
                    u.z = f2bf_bits(v[2]); u.w = f2bf_bits(v[3]);
                    *(ushort4*)(Cd + (size_t)rowg * ADIM + (colg - N1)) = u;
                } else {
                    if (RES) {
                        const ushort4 r4 = *(const ushort4*)(resid + (size_t)rowg * N + colg);
                        v[0] += bflo(r4.x); v[1] += bflo(r4.y);
                        v[2] += bflo(r4.z); v[3] += bflo(r4.w);
                    }
                    if (cf32) {
                        *(f32x4*)((float*)C + (size_t)(rowg + row_off) * N + colg) = v;
                    } else {
                        ushort4 u;
                        u.x = f2bf_bits(v[0]); u.y = f2bf_bits(v[1]);
                        u.z = f2bf_bits(v[2]); u.w = f2bf_bits(v[3]);
                        *(ushort4*)((bf16*)C + (size_t)(rowg + row_off) * (FD ? N1 : N) + colg) = u;
                    }
                }
            }
        }
        if (pass + 1 < NPASS) __syncthreads();
    }
}

// out_mode: 0 bf16, 1 f32 iff inputs f32 (final output), 2 f32 always.
// Dual-stream: pointers *0 used for M-tiles < split, *1 otherwise.
template<int TM, int ACT, bool RES, bool SCALE, bool FD>
__global__ __launch_bounds__(256)
void mfma_gemm_kernel(const int* __restrict__ flag, const bf16* __restrict__ A,
                      const void* W0, const void* W1, const void* Wd0, const void* Wd1,
                      const void* b0, const void* b1, const void* bd0, const void* bd1,
                      const bf16* __restrict__ resid, const void* sp0, const void* sp1,
                      void* __restrict__ C, bf16* __restrict__ Cd,
                      int out_mode, int row_off, int M, int N, int K, int split)
{
    __shared__ __align__(16) char SMEM[32768];
    if ((int)blockIdx.x * TM >= M) return;
    const bool isY = ((int)blockIdx.x * TM) >= split;
    const void* W = isY ? W1 : W0;
    const void* Wd = isY ? Wd1 : Wd0;
    const void* bb = isY ? b1 : b0;
    const void* bd = isY ? bd1 : bd0;
    const void* sp = isY ? sp1 : sp0;
    short* As = (short*)SMEM;
    short* Bs = As + TM * 64;
    float* Ep = (float*)SMEM;
    const bool cf32 = (out_mode == 2) || (out_mode == 1 && flag[0] != 0);
    if (flag[0])
        gemm_body<TM, ACT, RES, SCALE, FD, float>(A, (const float*)W, (const float*)Wd,
            (const float*)bb, (const float*)bd, resid, (const float*)sp, C, Cd,
            cf32, row_off, M, N, K, As, Bs, Ep);
    else
        gemm_body<TM, ACT, RES, SCALE, FD, bf16>(A, (const bf16*)W, (const bf16*)Wd,
            (const bf16*)bb, (const bf16*)bd, resid, (const bf16*)sp, C, Cd,
            cf32, row_off, M, N, K, As, Bs, Ep);
}

// ---------------------------------------------------------------------------
// Host orchestration
// ---------------------------------------------------------------------------
struct SW {
    const void *ln1_g, *ln1_b, *qkv_w, *qkv_b, *proj_w, *proj_b,
               *ln2_g, *ln2_b, *fc1_w, *fc1_b, *fc2_w, *fc2_b,
               *down_w, *down_b, *up_w, *up_b, *scale;
};

// qkv -> flash (regions) -> proj(+res) -> ln2 -> fc1+down -> fc2(+res) -> up(+res,scale)
static void stream_seq(const int* flag, bf16* t0, bf16* h, bf16* big, bf16* ah,
                       int M, int split, const SW& a, const SW& b,
                       void* outC, int row_off,
                       int npb0, int rows0, int npb1, int rows1, hipStream_t s)
{
    const dim3 gq(pad8((M + 127) / 128), 18);
    const dim3 gf(pad8((M + 127) / 128), 25);
    const dim3 g7(pad8((M + 63) / 64), 6);

    mfma_gemm_kernel<128, 0, false, false, false><<<gq, 256, 0, s>>>(flag, h,
        a.qkv_w, b.qkv_w, nullptr, nullptr, a.qkv_b, b.qkv_b, nullptr, nullptr,
        nullptr, nullptr, nullptr, big, nullptr, 0, 0, M, 2304, DMODEL, split);
    flash_attn_kernel<<<dim3((rows0 / npb0) * H_HEADS, (npb0 + 63) / 64), 256, 0, s>>>(big, h, npb0);
    if (rows1)
        flash_attn_kernel<<<dim3((rows1 / npb1) * H_HEADS, (npb1 + 63) / 64), 256, 0, s>>>(
            big + (size_t)rows0 * 2304, h + (size_t)rows0 * DMODEL, npb1);
    mfma_gemm_kernel<64, 0, true, false, false><<<g7, 256, 0, s>>>(flag, h,
        a.proj_w, b.proj_w, nullptr, nullptr, a.proj_b, b.proj_b, nullptr, nullptr,
        t0, nullptr, nullptr, t0, nullptr, 0, 0, M, DMODEL, DMODEL, split);
    ln_kernel<<<M, 256, 0, s>>>(flag, t0, a.ln2_g, a.ln2_b, b.ln2_g, b.ln2_b, h, split);
    mfma_gemm_kernel<128, 1, false, false, true><<<gf, 256, 0, s>>>(flag, h,
        a.fc1_w, b.fc1_w, a.down_w, b.down_w, a.fc1_b, b.fc1_b, a.down_b, b.down_b,
        nullptr, nullptr, nullptr, big, ah, 0, 0, M, DFF + ADIM, DMODEL, split);
    mfma_gemm_kernel<64, 0, true, false, false><<<g7, 256, 0, s>>>(flag, big,
        a.fc2_w, b.fc2_w, nullptr, nullptr, a.fc2_b, b.fc2_b, nullptr, nullptr,
        t0, nullptr, nullptr, t0, nullptr, 0, 0, M, DMODEL, DFF, split);
    mfma_gemm_kernel<64, 0, true, true, false><<<g7, 256, 0, s>>>(flag, ah,
        a.up_w, b.up_w, nullptr, nullptr, a.up_b, b.up_b, nullptr, nullptr,
        t0, a.scale, b.scale, outC, nullptr, 1, row_off, M, DMODEL, ADIM, split);
}

extern "C" void kernel_launch(void* const* d_in, const int* in_sizes, int n_in,
                              void* d_out, int out_size, void* d_ws, size_t ws_size,
                              hipStream_t stream)
{
    SW sw, rw;
    auto fill = [&](SW& s, int base) {
        s.ln1_g = d_in[base + 0];  s.ln1_b = d_in[base + 1];
        s.qkv_w = d_in[base + 2];  s.qkv_b = d_in[base + 3];
        s.proj_w = d_in[base + 4]; s.proj_b = d_in[base + 5];
        s.ln2_g = d_in[base + 6];  s.ln2_b = d_in[base + 7];
        s.fc1_w = d_in[base + 8];  s.fc1_b = d_in[base + 9];
        s.fc2_w = d_in[base + 10]; s.fc2_b = d_in[base + 11];
        s.down_w = d_in[base + 12]; s.down_b = d_in[base + 13];
        s.up_w = d_in[base + 14];  s.up_b = d_in[base + 15];
        s.scale = d_in[base + 16];
    };
    fill(sw, 5);
    fill(rw, 22);

    const int Mx = BATCH * NA;   // 8192
    const int My = BATCH * NV;   // 3136
    const int NOSPLIT = 1 << 30;

    const size_t szA = 256 + ((size_t)MTOT * DMODEL * 2 + (size_t)BATCH * NLAT * DMODEL
                     + (size_t)MTOT * DFF + (size_t)MTOT * ADIM) * 2;
    const size_t szB = 256 + ((size_t)Mx * DMODEL * 2 + (size_t)My * DMODEL
                     + (size_t)BATCH * NLAT * DMODEL + (size_t)Mx * DFF + (size_t)Mx * ADIM) * 2;

    int* flag = (int*)d_ws;
    detect_dtype_kernel<<<1, 64, 0, stream>>>((const unsigned short*)d_in[0], flag);

    if (ws_size >= szA) {
        // ---- Path A: combined streams, M = 11328 ----
        char* base = (char*)d_ws + 256;
        bf16* t0 = (bf16*)base;      base += (size_t)MTOT * DMODEL * 2;
        bf16* fused = (bf16*)base;   base += (size_t)BATCH * NLAT * DMODEL * 2;
        bf16* h = (bf16*)base;       base += (size_t)MTOT * DMODEL * 2;
        bf16* big = (bf16*)base;     base += (size_t)MTOT * DFF * 2;
        bf16* ah = (bf16*)base;

        bf16* Cc = h;                       // 17.4MB == h exactly
        bf16* Lb = ah;                      // 48KB <= 1.45MB
        float* scores = (float*)big;        // 1.45MB
        float* P = (float*)((char*)big + 2 * 1024 * 1024);

        pack_concat_kernel<<<MCAT + NLAT, 256, 0, stream>>>(flag, d_in[0], d_in[1], d_in[2], Cc, Lb);
        mfma_gemm_kernel<128, 0, false, false, false><<<dim3(pad8((MCAT + 127) / 128), 1), 256, 0, stream>>>(
            flag + 1, Cc, Lb, Lb, nullptr, nullptr, nullptr, nullptr, nullptr, nullptr,
            nullptr, nullptr, nullptr, scores, nullptr, 2, 0, MCAT, NLAT, DMODEL, NOSPLIT);
        fusion_softmax_kernel<<<BATCH * NLAT, 64, 0, stream>>>(scores, P);
        fusion_wsum_kernel<<<dim3(DMODEL / 128, BATCH), 256, 0, stream>>>(Cc, P, fused);

        attend_fused_kernel<<<BATCH * NA, 256, 0, stream>>>(
            flag, d_in[0], fused, d_in[3], sw.ln1_g, sw.ln1_b, t0, h, NA);
        attend_fused_kernel<<<BATCH * NV, 256, 0, stream>>>(
            flag, d_in[1], fused, d_in[4], rw.ln1_g, rw.ln1_b,
            t0 + (size_t)Mx * DMODEL, h + (size_t)Mx * DMODEL, NV);

        stream_seq(flag, t0, h, big, ah, MTOT, Mx, sw, rw, d_out, 0,
                   NA, Mx, NV, My, stream);
    } else if (ws_size >= szB) {
        // ---- Path B: split streams sharing Mx-sized buffers ----
        char* base = (char*)d_ws + 256;
        bf16* x1 = (bf16*)base;      base += (size_t)Mx * DMODEL * 2;
        bf16* y1 = (bf16*)base;      base += (size_t)My * DMODEL * 2;
        bf16* fused = (bf16*)base;   base += (size_t)BATCH * NLAT * DMODEL * 2;
        bf16* h = (bf16*)base;       base += (size_t)Mx * DMODEL * 2;
        bf16* big = (bf16*)base;     base += (size_t)Mx * DFF * 2;
        bf16* ah = (bf16*)base;

        bf16* Cc = big;
        bf16* Lb = ah;
        float* scores = (float*)((char*)big + 18 * 1024 * 1024);
        float* P = (float*)((char*)big + 20 * 1024 * 1024);

        pack_concat_kernel<<<MCAT + NLAT, 256, 0, stream>>>(flag, d_in[0], d_in[1], d_in[2], Cc, Lb);
        mfma_gemm_kernel<128, 0, false, false, false><<<dim3(pad8((MCAT + 127) / 128), 1), 256, 0, stream>>>(
            flag + 1, Cc, Lb, Lb, nullptr, nullptr, nullptr, nullptr, nullptr, nullptr,
            nullptr, nullptr, nullptr, scores, nullptr, 2, 0, MCAT, NLAT, DMODEL, NOSPLIT);
        fusion_softmax_kernel<<<BATCH * NLAT, 64, 0, stream>>>(scores, P);
        fusion_wsum_kernel<<<dim3(DMODEL / 128, BATCH), 256, 0, stream>>>(Cc, P, fused);

        attend_fused_kernel<<<BATCH * NA, 256, 0, stream>>>(
            flag, d_in[0], fused, d_in[3], sw.ln1_g, sw.ln1_b, x1, h, NA);
        stream_seq(flag, x1, h, big, ah, Mx, NOSPLIT, sw, sw, d_out, 0, NA, Mx, 0, 0, stream);

        attend_fused_kernel<<<BATCH * NV, 256, 0, stream>>>(
            flag, d_in[1], fused, d_in[4], rw.ln1_g, rw.ln1_b, y1, h, NV);
        stream_seq(flag, y1, h, big, ah, My, NOSPLIT, rw, rw, d_out, Mx, NV, My, 0, 0, stream);
    } else {
        // ---- Path C: chunked x-stream (My-sized shared buffers) ----
        char* base = (char*)d_ws + 256;
        bf16* x1 = (bf16*)base;      base += (size_t)Mx * DMODEL * 2;
        bf16* y1 = (bf16*)base;      base += (size_t)My * DMODEL * 2;
        bf16* fused = (bf16*)base;   base += (size_t)BATCH * NLAT * DMODEL * 2;
        bf16* h = (bf16*)base;       base += (size_t)My * DMODEL * 2;
        bf16* big = (bf16*)base;     base += (size_t)My * DFF * 2;
        bf16* ah = (bf16*)base;

        bf16* Cc = big;                               // 17.4 <= 19.3MB
        bf16* Lb = ah;
        float* scores = (float*)((char*)big + 17500160);
        float* P = (float*)h;                         // 1.57 <= 4.8MB

        pack_concat_kernel<<<MCAT + NLAT, 256, 0, stream>>>(flag, d_in[0], d_in[1], d_in[2], Cc, Lb);
        mfma_gemm_kernel<128, 0, false, false, false><<<dim3(pad8((MCAT + 127) / 128), 1), 256, 0, stream>>>(
            flag + 1, Cc, Lb, Lb, nullptr, nullptr, nullptr, nullptr, nullptr, nullptr,
            nullptr, nullptr, nullptr, scores, nullptr, 2, 0, MCAT, NLAT, DMODEL, NOSPLIT);
        fusion_softmax_kernel<<<BATCH * NLAT, 64, 0, stream>>>(scores, P);
        fusion_wsum_kernel<<<dim3(DMODEL / 128, BATCH), 256, 0, stream>>>(Cc, P, fused);

        attend_fused_kernel<<<BATCH * NA, 256, 0, stream>>>(
            flag, d_in[0], fused, d_in[3], sw.ln1_g, sw.ln1_b, x1, nullptr, NA);
        const int MCH = 2048;
        for (int c = 0; c < Mx / MCH; c++) {
            bf16* t0c = x1 + (size_t)c * MCH * DMODEL;
            ln_kernel<<<MCH, 256, 0, stream>>>(flag, t0c, sw.ln1_g, sw.ln1_b,
                                               sw.ln1_g, sw.ln1_b, h, NOSPLIT);
            stream_seq(flag, t0c, h, big, ah, MCH, NOSPLIT, sw, sw, d_out, c * MCH,
                       NA, MCH, 0, 0, stream);
        }
        attend_fused_kernel<<<BATCH * NV, 256, 0, stream>>>(
            flag, d_in[1], fused, d_in[4], rw.ln1_g, rw.ln1_b, y1, h, NV);
        stream_seq(flag, y1, h, big, ah, My, NOSPLIT, rw, rw, d_out, Mx, NV, My, 0, 0, stream);
    }
}